// Round 6
// baseline (1220.088 us; speedup 1.0000x reference)
//
#include <hip/hip_runtime.h>
#include <math.h>

#define BB   64
#define SS   1024
#define DD   256
#define H2   512
#define FF   128
#define TT   64
#define NSEG 128
#define DIN  1152
#define G4   2048
#define MROWS 8192   /* B*NSEG */
#define MX   65536   /* B*S   */

typedef __attribute__((ext_vector_type(8))) short bf16x8;
typedef __attribute__((ext_vector_type(4))) float f32x4;

__device__ __forceinline__ unsigned short f2b(float f){
    union { float f; unsigned u; } v; v.f = f;
    unsigned r = v.u + 0x7fffu + ((v.u >> 16) & 1u);
    return (unsigned short)(r >> 16);
}
__device__ __forceinline__ float b2f(unsigned short h){
    union { unsigned u; float f; } v; v.u = ((unsigned)h) << 16;
    return v.f;
}
__device__ __forceinline__ float fsig(float x){
    return 1.f / (1.f + __expf(-x));
}
__device__ __forceinline__ float ftanh(float x){
    float e = __expf(-2.f * fabsf(x));
    float r = (1.f - e) / (1.f + e);
    return x < 0.f ? -r : r;
}

// ---------------- prep kernels ----------------

__global__ void k_cvt(const float* __restrict__ src, unsigned short* __restrict__ dst, int n){
    int i = blockIdx.x * 256 + threadIdx.x;
    if (i < n) dst[i] = f2b(src[i]);
}

// Wf [768][256] rows: 0..127 c1t0 | 128..255 c2t0 | 256..383 c2t1 | 384..511 c3t0 | 512..639 c3t1 | 640..767 c3t2
__global__ void k_wf(const float* __restrict__ w1, const float* __restrict__ w2,
                     const float* __restrict__ w3, unsigned short* __restrict__ Wf){
    int i = blockIdx.x * 256 + threadIdx.x;       // 768*256
    int col = i >> 8, d = i & 255;
    float v;
    if (col < 128)      v = w1[col * 256 + d];
    else if (col < 384) { int f = (col - 128) & 127; int tap = (col - 128) >> 7; v = w2[f * 512 + tap * 256 + d]; }
    else                { int c = col - 384; int f = c & 127; int tap = c >> 7;  v = w3[f * 768 + tap * 256 + d]; }
    Wf[i] = f2b(v);
}

// W_fc [64][512] -> W_fc_t [512][64] fp32
__global__ void k_tr_wfc(const float* __restrict__ src, float* __restrict__ dst){
    int i = blockIdx.x * 256 + threadIdx.x;       // 32768
    int v = i >> 9, k = i & 511;
    dst[k * 64 + v] = src[i];
}

// X[row][d] = bf16(embed[word_ids[row]][d]), row in [0, MX)
__global__ void k_gather(const int* __restrict__ wid, const float* __restrict__ embed,
                         unsigned short* __restrict__ X){
    int i = blockIdx.x * 256 + threadIdx.x;       // MX*64
    int row = i >> 6, d4 = i & 63;
    int w = wid[row];
    float4 v = *(const float4*)(embed + (size_t)w * DD + d4 * 4);
    ushort4 o; o.x = f2b(v.x); o.y = f2b(v.y); o.z = f2b(v.z); o.w = f2b(v.w);
    *(ushort4*)(X + (size_t)row * DD + d4 * 4) = o;
}

// c_w: dec[row][0..256) = mean of 8 X rows
__global__ void k_cw(const unsigned short* __restrict__ X, unsigned short* __restrict__ dec){
    int i = blockIdx.x * 256 + threadIdx.x;       // MROWS*256
    int row = i >> 8, d = i & 255;
    const unsigned short* p = X + (size_t)row * 8 * DD + d;
    float s = 0.f;
#pragma unroll
    for (int t = 0; t < 8; t++) s += b2f(p[t * DD]);
    dec[(size_t)row * DIN + d] = f2b(s * 0.125f);
}

// c_h: dec[row][256..768) = mean of 8 encoder rows
__global__ void k_ch(const float* __restrict__ enc, unsigned short* __restrict__ dec){
    int i = blockIdx.x * 256 + threadIdx.x;       // MROWS*512
    int row = i >> 9, c = i & 511;
    const float* p = enc + (size_t)row * 8 * H2 + c;
    float s = 0.f;
#pragma unroll
    for (int t = 0; t < 8; t++) s += p[t * H2];
    dec[(size_t)row * DIN + 256 + c] = f2b(s * 0.125f);
}

// h0 into Hbuf[0], batch-major: Hbuf[0][b][c]. Clamp so bit14 (sentinel) can never be set.
__global__ void k_h0(const float* __restrict__ enc, unsigned short* __restrict__ Hbuf){
    int i = blockIdx.x * 256 + threadIdx.x;       // 64*512
    int b = i >> 9, c = i & 511;
    float v = (c < 256) ? enc[(size_t)b * SS * H2 + (size_t)(SS - 1) * H2 + c]
                        : enc[(size_t)b * SS * H2 + c];
    v = fminf(fmaxf(v, -1.875f), 1.875f);
    Hbuf[(size_t)b * 512 + c] = f2b(v);
}

// fill Hbuf steps 1..128 with sentinel (bit14 set => "not yet written").
// legit h = sigma*tanh in (-1,1): bf16 bit14 is clear for all |v| < 2.
__global__ void k_fill(uint4* __restrict__ p){
    int i = blockIdx.x * 256 + threadIdx.x;       // 2048*256 = 524288 uint4 = 8 MB
    uint4 v; v.x = v.y = v.z = v.w = 0x7FC07FC0u;
    p[i] = v;
}

// ---------------- generic BT GEMM: C[M][N] = A[M][K] * Bm[N][K]^T, bf16 in/out ----------------
__global__ __launch_bounds__(256) void gemm_bt(
    const unsigned short* __restrict__ A, const unsigned short* __restrict__ Bm,
    unsigned short* __restrict__ C, int M, int N, int K)
{
    __shared__ unsigned short As[128][40];
    __shared__ unsigned short Bs[128][40];
    const int tid = threadIdx.x;
    const int m0 = blockIdx.y * 128, n0 = blockIdx.x * 128;
    const int w = tid >> 6, lane = tid & 63;
    const int lm = lane & 15, quad = lane >> 4;
    const int wm = (w >> 1) * 64, wn = (w & 1) * 64;

    const f32x4 z = {0.f, 0.f, 0.f, 0.f};
    f32x4 acc[4][4];
#pragma unroll
    for (int i = 0; i < 4; i++)
#pragma unroll
        for (int j = 0; j < 4; j++) acc[i][j] = z;

    const int r0 = tid >> 2;            // 0..63
    const int kp = (tid & 3) * 8;       // 0,8,16,24 (bf16 units)

    for (int kc = 0; kc < K; kc += 32){
        uint4 a0 = *(const uint4*)(A + (size_t)(m0 + r0) * K + kc + kp);
        uint4 a1 = *(const uint4*)(A + (size_t)(m0 + 64 + r0) * K + kc + kp);
        uint4 b0 = *(const uint4*)(Bm + (size_t)(n0 + r0) * K + kc + kp);
        uint4 b1 = *(const uint4*)(Bm + (size_t)(n0 + 64 + r0) * K + kc + kp);
        __syncthreads();
        *(uint4*)&As[r0][kp] = a0;
        *(uint4*)&As[64 + r0][kp] = a1;
        *(uint4*)&Bs[r0][kp] = b0;
        *(uint4*)&Bs[64 + r0][kp] = b1;
        __syncthreads();
        bf16x8 af[4], bf[4];
#pragma unroll
        for (int mt = 0; mt < 4; mt++) af[mt] = *(const bf16x8*)&As[wm + mt * 16 + lm][quad * 8];
#pragma unroll
        for (int nt = 0; nt < 4; nt++) bf[nt] = *(const bf16x8*)&Bs[wn + nt * 16 + lm][quad * 8];
#pragma unroll
        for (int mt = 0; mt < 4; mt++)
#pragma unroll
            for (int nt = 0; nt < 4; nt++)
                acc[mt][nt] = __builtin_amdgcn_mfma_f32_16x16x32_bf16(af[mt], bf[nt], acc[mt][nt], 0, 0, 0);
    }
#pragma unroll
    for (int mt = 0; mt < 4; mt++){
        int mrow = m0 + wm + mt * 16 + quad * 4;
#pragma unroll
        for (int nt = 0; nt < 4; nt++){
            int ncol = n0 + wn + nt * 16 + lm;
#pragma unroll
            for (int r = 0; r < 4; r++)
                C[(size_t)(mrow + r) * N + ncol] = f2b(acc[mt][nt][r]);
        }
    }
}

// ---- gates GEMM: same compute, epilogue writes the group/block-tiled layout ----
// Consumer block nb = grp*16+gb (grp = b>>4, gb = hcol>>5) owns local cols n = (hcol&31)*4 + gate.
// dst element: ((nb*128 + t)*128 + n)*16 + (b&15)   -> 4KB contiguous per (nb,t)
__global__ __launch_bounds__(256) void gemm_bt_gates(
    const unsigned short* __restrict__ A, const unsigned short* __restrict__ Bm,
    unsigned short* __restrict__ C, int M, int N, int K)
{
    __shared__ unsigned short As[128][40];
    __shared__ unsigned short Bs[128][40];
    const int tid = threadIdx.x;
    const int m0 = blockIdx.y * 128, n0 = blockIdx.x * 128;
    const int w = tid >> 6, lane = tid & 63;
    const int lm = lane & 15, quad = lane >> 4;
    const int wm = (w >> 1) * 64, wn = (w & 1) * 64;

    const f32x4 z = {0.f, 0.f, 0.f, 0.f};
    f32x4 acc[4][4];
#pragma unroll
    for (int i = 0; i < 4; i++)
#pragma unroll
        for (int j = 0; j < 4; j++) acc[i][j] = z;

    const int r0 = tid >> 2;
    const int kp = (tid & 3) * 8;

    for (int kc = 0; kc < K; kc += 32){
        uint4 a0 = *(const uint4*)(A + (size_t)(m0 + r0) * K + kc + kp);
        uint4 a1 = *(const uint4*)(A + (size_t)(m0 + 64 + r0) * K + kc + kp);
        uint4 b0 = *(const uint4*)(Bm + (size_t)(n0 + r0) * K + kc + kp);
        uint4 b1 = *(const uint4*)(Bm + (size_t)(n0 + 64 + r0) * K + kc + kp);
        __syncthreads();
        *(uint4*)&As[r0][kp] = a0;
        *(uint4*)&As[64 + r0][kp] = a1;
        *(uint4*)&Bs[r0][kp] = b0;
        *(uint4*)&Bs[64 + r0][kp] = b1;
        __syncthreads();
        bf16x8 af[4], bf[4];
#pragma unroll
        for (int mt = 0; mt < 4; mt++) af[mt] = *(const bf16x8*)&As[wm + mt * 16 + lm][quad * 8];
#pragma unroll
        for (int nt = 0; nt < 4; nt++) bf[nt] = *(const bf16x8*)&Bs[wn + nt * 16 + lm][quad * 8];
#pragma unroll
        for (int mt = 0; mt < 4; mt++)
#pragma unroll
            for (int nt = 0; nt < 4; nt++)
                acc[mt][nt] = __builtin_amdgcn_mfma_f32_16x16x32_bf16(af[mt], bf[nt], acc[mt][nt], 0, 0, 0);
    }
#pragma unroll
    for (int mt = 0; mt < 4; mt++){
        int mrow = m0 + wm + mt * 16 + quad * 4;
#pragma unroll
        for (int nt = 0; nt < 4; nt++){
            int ncol = n0 + wn + nt * 16 + lm;
            int g = ncol >> 9, c = ncol & 511;
            int gb = c >> 5, hcl = c & 31;
            int n = hcl * 4 + g;
#pragma unroll
            for (int r = 0; r < 4; r++){
                int m = mrow + r;                   // = b*128 + t
                int b = m >> 7, t = m & 127;
                int grp = b >> 4, bl = b & 15;
                size_t dst = (((size_t)(grp * 16 + gb) * NSEG + t) * 128 + n) * 16 + bl;
                C[dst] = f2b(acc[mt][nt][r]);
            }
        }
    }
}

// ---------------- conv max-pool: G[MX rows][N] -> dec[:,768+colofs..] ----------------
__global__ void k_pool(const unsigned short* __restrict__ G, const float* __restrict__ bias,
                       unsigned short* __restrict__ dec, int taps, int colofs){
    int i = blockIdx.x * 256 + threadIdx.x;       // MROWS*128
    int row = i >> 7, f = i & 127;
    int N = taps * 128;
    float mx = -1e30f;
    for (int t = 0; t <= 8 - taps; t++){
        float a = 0.f;
        for (int tap = 0; tap < taps; tap++)
            a += b2f(G[(size_t)(row * 8 + t + tap) * N + tap * 128 + f]);
        mx = fmaxf(mx, a);
    }
    mx = fmaxf(mx + bias[f], 0.f);
    dec[(size_t)row * DIN + 768 + colofs + f] = f2b(mx);
}

// ---------------- persistent LSTM recurrence: 4 groups x 16 blocks, 8 waves/block ----------------
// Round-5 structure (fan-in 16, sentinel-on-data sync, 8 waves = 2/SIMD) with the W-residency
// fix: round 5's VGPR_Count=64 proves the "+v" pin was defeated by rematerialization (the
// compiler re-loads W from the const Whh pointer each iteration). Now each W fragment is
// produced by asm volatile global_load_dwordx4 -- a volatile asm cannot be re-executed, so
// the 16 results (64 VGPRs) must stay live across the t-loop. s_waitcnt vmcnt(0) +
// sched_barrier(0) fence the first-iteration MFMA from hoisting past the loads (rule #18).
// In-loop W traffic: ZERO. Signature if it worked: VGPR ~120-170, no scratch.
// Hbuf layout per step: [b:64][c:512] bf16, batch-major.
// gxt layout: [nb:64][t:128][n:128][bl:16], 4KB chunk per (nb,t).
__global__ __launch_bounds__(512, 2) void k_lstm(
    const unsigned short* __restrict__ gxt,  // blocked gate pre-activations, bf16
    const unsigned short* __restrict__ Whh,  // [2048][512] bf16
    unsigned short* __restrict__ Hbuf)       // [129][64*512]
{
    __shared__ unsigned short h_lds[2][16 * 512];   // 2 x 16KB, double-buffered

    const int tid = threadIdx.x;
    const int nb = blockIdx.x;
    const int grp = nb >> 4, gb = nb & 15;
    const int w = tid >> 6, lane = tid & 63, lm = lane & 15, quad = lane >> 4;
    const int g = lm & 3;

    // --- W fragments in registers via non-rematerializable volatile loads ---
    // wave w owns local gate-cols n = w*16 + lm; global W row = (n&3)*512 + gb*32 + (n>>2);
    // fragment ks: cols ks*32 + quad*8 .. +8
    bf16x8 wf[16];
    {
        int n = w * 16 + lm;
        const unsigned short* p = Whh + (size_t)((n & 3) * 512 + gb * 32 + (n >> 2)) * H2 + quad * 8;
#pragma unroll
        for (int ks = 0; ks < 16; ks++){
            const void* ap = (const void*)(p + ks * 32);
            asm volatile("global_load_dwordx4 %0, %1, off" : "=&v"(wf[ks]) : "v"(ap));
        }
        asm volatile("s_waitcnt vmcnt(0)" ::: "memory");
        __builtin_amdgcn_sched_barrier(0);
    }

    float cst[4] = {0.f, 0.f, 0.f, 0.f};

    union Chunk { unsigned long long q[2]; uint4 u4; };

    for (int t = 0; t < NSEG; t++){
        // --- issue this thread's 2 h-chunks (16B each) of the group's 16KB region ---
        const unsigned short* hsrc = Hbuf + (size_t)t * (BB * H2) + (size_t)grp * (16 * H2);
        Chunk ch[2];
#pragma unroll
        for (int j = 0; j < 2; j++){
            const unsigned long long* p = (const unsigned long long*)(hsrc + (size_t)(j * 512 + tid) * 8);
            ch[j].q[0] = __hip_atomic_load(p,     __ATOMIC_RELAXED, __HIP_MEMORY_SCOPE_AGENT);
            ch[j].q[1] = __hip_atomic_load(p + 1, __ATOMIC_RELAXED, __HIP_MEMORY_SCOPE_AGENT);
        }

        // --- gate pre-activations (normal cached loads, independent) ---
        const unsigned short* gchunk = gxt + ((size_t)nb * NSEG + t) * 2048;
        ushort4 pr = *(const ushort4*)(gchunk + (w * 16 + lm) * 16 + quad * 4);

        // --- sentinel poll with backoff: retry only missing chunks ---
        unsigned pend = 0x3u;
        while (pend){
            unsigned np = 0;
#pragma unroll
            for (int j = 0; j < 2; j++){
                if (pend & (1u << j)){
                    if (((ch[j].q[0] | ch[j].q[1]) & 0x4000400040004000ULL) != 0ULL){
                        const unsigned long long* p = (const unsigned long long*)(hsrc + (size_t)(j * 512 + tid) * 8);
                        ch[j].q[0] = __hip_atomic_load(p,     __ATOMIC_RELAXED, __HIP_MEMORY_SCOPE_AGENT);
                        ch[j].q[1] = __hip_atomic_load(p + 1, __ATOMIC_RELAXED, __HIP_MEMORY_SCOPE_AGENT);
                        np |= 1u << j;
                    }
                }
            }
            pend = np;
            if (pend) __builtin_amdgcn_s_sleep(1);
        }

        // --- stage h to LDS, XOR-swizzled (row = byte>>10; byte ^= (row&7)<<4) ---
        char* hb = (char*)&h_lds[t & 1][0];
#pragma unroll
        for (int j = 0; j < 2; j++){
            unsigned addr = (unsigned)(j * 512 + tid) * 16u;
            addr ^= ((addr >> 10) & 7u) << 4;
            *(uint4*)(hb + addr) = ch[j].u4;
        }
        __syncthreads();

        // --- MFMA: A (h) from LDS, B (W) from resident registers; 16-deep acc chain ---
        const unsigned hrowb = (unsigned)lm << 10;
        const unsigned swz = (unsigned)(lm & 7) << 4;
        f32x4 acc = {0.f, 0.f, 0.f, 0.f};
#pragma unroll
        for (int ks = 0; ks < 16; ks++){
            unsigned colb = ((unsigned)ks << 6) + ((unsigned)quad << 4);
            bf16x8 avv = *(const bf16x8*)(hb + ((hrowb + colb) ^ swz));
            acc = __builtin_amdgcn_mfma_f32_16x16x32_bf16(avv, wf[ks], acc, 0, 0, 0);
        }

        // --- epilogue: gather i/f/g/o across the 4-lane gate group (g = lm&3) ---
        const unsigned short* prs = (const unsigned short*)&pr;
        unsigned short hv4[4];
#pragma unroll
        for (int r = 0; r < 4; r++){
            float a = acc[r] + b2f(prs[r]);
            float bsw = __shfl_xor(a, 1);
            float p  = (g & 1) ? bsw : a;     // i or g
            float qq = (g & 1) ? a : bsw;     // f or o
            float c2 = __shfl_xor(p, 2);
            float d2 = __shfl_xor(qq, 2);
            float iv = (g & 2) ? c2 : p;
            float gv = (g & 2) ? p  : c2;
            float fv = (g & 2) ? d2 : qq;
            float ov = (g & 2) ? qq : d2;
            float si = fsig(iv), sf = fsig(fv), so = fsig(ov);
            float cn = sf * cst[r] + si * ftanh(gv);
            cst[r] = cn;
            unsigned short hv = f2b(so * ftanh(cn));
            if (hv & 0x4000u) hv = 0;         // insurance: never emit a sentinel pattern
            hv4[r] = hv;
        }

        // --- publish: shfl-pack 4 cols (lanes lm = 0,4,8,12 hold cols w*4+0..3) -> 8B stores ---
        // lane lm==0 of each quad assembles batch (quad*4+r)'s 4-col row chunk and stores it.
#pragma unroll
        for (int r = 0; r < 4; r++){
            unsigned v01 = (unsigned)hv4[r] | ((unsigned)(unsigned short)__shfl_xor((int)hv4[r], 4) << 16);
            unsigned v23 = (unsigned)__shfl_xor((int)v01, 8);
            unsigned long long outq = (unsigned long long)v01 | ((unsigned long long)v23 << 32);
            if (lm == 0){
                int bt = grp * 16 + quad * 4 + r;
                unsigned long long* dp = (unsigned long long*)
                    (Hbuf + (size_t)(t + 1) * (BB * H2) + (size_t)bt * H2 + gb * 32 + w * 4);
                __hip_atomic_store(dp, outq, __ATOMIC_RELAXED, __HIP_MEMORY_SCOPE_AGENT);
            }
        }
        asm volatile("" ::: "memory");   // pin the h stores inside this iteration
    }
}

// ---------------- output projection + log_softmax ----------------
__global__ __launch_bounds__(256) void k_out(
    const unsigned short* __restrict__ Hbuf, const float* __restrict__ Wt, float* __restrict__ out)
{
    __shared__ float hsh[4][H2];
    const int w = threadIdx.x >> 6, lane = threadIdx.x & 63;
    const int row = blockIdx.x * 4 + w;          // 0..8191 = b*128 + t
    const int b = row >> 7, t = row & 127;
    const unsigned short* hp = Hbuf + (size_t)(t + 1) * (BB * H2) + (size_t)b * H2;
    uint4 hv = *(const uint4*)(hp + lane * 8);
    const unsigned short* hs = (const unsigned short*)&hv;
#pragma unroll
    for (int i = 0; i < 8; i++) hsh[w][lane * 8 + i] = b2f(hs[i]);
    __syncthreads();
    float acc = 0.f;
#pragma unroll 8
    for (int k = 0; k < H2; k++)
        acc = fmaf(hsh[w][k], Wt[k * 64 + lane], acc);
    float m = acc;
#pragma unroll
    for (int off = 32; off; off >>= 1) m = fmaxf(m, __shfl_xor(m, off));
    float e = expf(acc - m), s = e;
#pragma unroll
    for (int off = 32; off; off >>= 1) s += __shfl_xor(s, off);
    out[(size_t)row * TT + lane] = acc - m - logf(s);
}

// ---------------- launcher ----------------
extern "C" void kernel_launch(void* const* d_in, const int* in_sizes, int n_in,
                              void* d_out, int out_size, void* d_ws, size_t ws_size,
                              hipStream_t stream)
{
    const int*   wid = (const int*)d_in[0];
    const float* emb = (const float*)d_in[1];
    const float* enc = (const float*)d_in[2];
    const float* wc1 = (const float*)d_in[3];
    const float* bc1 = (const float*)d_in[4];
    const float* wc2 = (const float*)d_in[5];
    const float* bc2 = (const float*)d_in[6];
    const float* wc3 = (const float*)d_in[7];
    const float* bc3 = (const float*)d_in[8];
    const float* wih = (const float*)d_in[9];
    const float* whh = (const float*)d_in[10];
    const float* wfc = (const float*)d_in[11];

    char* ws = (char*)d_ws;
    size_t off = 0;
    auto alloc = [&](size_t bytes) -> void* {
        void* p = ws + off; off += (bytes + 255) & ~(size_t)255; return p;
    };
    unsigned short* X    = (unsigned short*)alloc((size_t)MX * DD * 2);      // 33.5 MB (reused as Hbuf)
    unsigned short* dec  = (unsigned short*)alloc((size_t)MROWS * DIN * 2);  // 18.9 MB
    unsigned short* Gb   = (unsigned short*)alloc((size_t)MX * 384 * 2);     // 50.3 MB (reused as gates)
    unsigned short* Wfb  = (unsigned short*)alloc((size_t)768 * 256 * 2);
    unsigned short* Wihb = (unsigned short*)alloc((size_t)G4 * DIN * 2);
    unsigned short* Whhb = (unsigned short*)alloc((size_t)G4 * H2 * 2);
    float*          Wfct = (float*)alloc((size_t)H2 * TT * 4);
    unsigned short* Hbuf  = X;    // X dead after conv GEMM pass 3
    unsigned short* gates = Gb;   // G dead after pool3

    k_cvt<<<(G4 * DIN + 255) / 256, 256, 0, stream>>>(wih, Wihb, G4 * DIN);
    k_cvt<<<(G4 * H2 + 255) / 256, 256, 0, stream>>>(whh, Whhb, G4 * H2);
    k_wf<<<768, 256, 0, stream>>>(wc1, wc2, wc3, Wfb);
    k_tr_wfc<<<128, 256, 0, stream>>>(wfc, Wfct);
    k_gather<<<MX / 4, 256, 0, stream>>>(wid, emb, X);
    k_cw<<<MROWS, 256, 0, stream>>>(X, dec);
    k_ch<<<MROWS * 2, 256, 0, stream>>>(enc, dec);

    gemm_bt<<<dim3(1, 512), 256, 0, stream>>>(X, Wfb,                         Gb, MX, 128, 256);
    k_pool<<<4096, 256, 0, stream>>>(Gb, bc1, dec, 1, 0);
    gemm_bt<<<dim3(2, 512), 256, 0, stream>>>(X, Wfb + (size_t)128 * 256,     Gb, MX, 256, 256);
    k_pool<<<4096, 256, 0, stream>>>(Gb, bc2, dec, 2, 128);
    gemm_bt<<<dim3(3, 512), 256, 0, stream>>>(X, Wfb + (size_t)384 * 256,     Gb, MX, 384, 256);
    k_pool<<<4096, 256, 0, stream>>>(Gb, bc3, dec, 3, 256);

    // X dead after conv GEMM pass 3: init Hbuf[0] (h0) and sentinel-fill steps 1..128
    k_h0<<<BB * H2 / 256, 256, 0, stream>>>(enc, Hbuf);
    k_fill<<<2048, 256, 0, stream>>>((uint4*)(Hbuf + BB * H2));

    gemm_bt_gates<<<dim3(16, 64), 256, 0, stream>>>(dec, Wihb, gates, MROWS, G4, DIN);
    k_lstm<<<64, 512, 0, stream>>>(gates, Whhb, Hbuf);
    k_out<<<2048, 256, 0, stream>>>(Hbuf, Wfct, (float*)d_out);
}

// Round 7
// 1059.786 us; speedup vs baseline: 1.1513x; 1.1513x over previous
//
#include <hip/hip_runtime.h>
#include <math.h>

#define BB   64
#define SS   1024
#define DD   256
#define H2   512
#define FF   128
#define TT   64
#define NSEG 128
#define DIN  1152
#define G4   2048
#define MROWS 8192   /* B*NSEG */
#define MX   65536   /* B*S   */

typedef __attribute__((ext_vector_type(8))) short bf16x8;
typedef __attribute__((ext_vector_type(4))) float f32x4;

__device__ __forceinline__ unsigned short f2b(float f){
    union { float f; unsigned u; } v; v.f = f;
    unsigned r = v.u + 0x7fffu + ((v.u >> 16) & 1u);
    return (unsigned short)(r >> 16);
}
__device__ __forceinline__ float b2f(unsigned short h){
    union { unsigned u; float f; } v; v.u = ((unsigned)h) << 16;
    return v.f;
}
__device__ __forceinline__ float fsig(float x){
    return 1.f / (1.f + __expf(-x));
}
__device__ __forceinline__ float ftanh(float x){
    float e = __expf(-2.f * fabsf(x));
    float r = (1.f - e) / (1.f + e);
    return x < 0.f ? -r : r;
}

// ---------------- prep kernels ----------------

__global__ void k_cvt(const float* __restrict__ src, unsigned short* __restrict__ dst, int n){
    int i = blockIdx.x * 256 + threadIdx.x;
    if (i < n) dst[i] = f2b(src[i]);
}

// Wf [768][256] rows: 0..127 c1t0 | 128..255 c2t0 | 256..383 c2t1 | 384..511 c3t0 | 512..639 c3t1 | 640..767 c3t2
__global__ void k_wf(const float* __restrict__ w1, const float* __restrict__ w2,
                     const float* __restrict__ w3, unsigned short* __restrict__ Wf){
    int i = blockIdx.x * 256 + threadIdx.x;       // 768*256
    int col = i >> 8, d = i & 255;
    float v;
    if (col < 128)      v = w1[col * 256 + d];
    else if (col < 384) { int f = (col - 128) & 127; int tap = (col - 128) >> 7; v = w2[f * 512 + tap * 256 + d]; }
    else                { int c = col - 384; int f = c & 127; int tap = c >> 7;  v = w3[f * 768 + tap * 256 + d]; }
    Wf[i] = f2b(v);
}

// W_fc [64][512] -> W_fc_t [512][64] fp32
__global__ void k_tr_wfc(const float* __restrict__ src, float* __restrict__ dst){
    int i = blockIdx.x * 256 + threadIdx.x;       // 32768
    int v = i >> 9, k = i & 511;
    dst[k * 64 + v] = src[i];
}

// X[row][d] = bf16(embed[word_ids[row]][d]), row in [0, MX)
__global__ void k_gather(const int* __restrict__ wid, const float* __restrict__ embed,
                         unsigned short* __restrict__ X){
    int i = blockIdx.x * 256 + threadIdx.x;       // MX*64
    int row = i >> 6, d4 = i & 63;
    int w = wid[row];
    float4 v = *(const float4*)(embed + (size_t)w * DD + d4 * 4);
    ushort4 o; o.x = f2b(v.x); o.y = f2b(v.y); o.z = f2b(v.z); o.w = f2b(v.w);
    *(ushort4*)(X + (size_t)row * DD + d4 * 4) = o;
}

// c_w: dec[row][0..256) = mean of 8 X rows
__global__ void k_cw(const unsigned short* __restrict__ X, unsigned short* __restrict__ dec){
    int i = blockIdx.x * 256 + threadIdx.x;       // MROWS*256
    int row = i >> 8, d = i & 255;
    const unsigned short* p = X + (size_t)row * 8 * DD + d;
    float s = 0.f;
#pragma unroll
    for (int t = 0; t < 8; t++) s += b2f(p[t * DD]);
    dec[(size_t)row * DIN + d] = f2b(s * 0.125f);
}

// c_h: dec[row][256..768) = mean of 8 encoder rows
__global__ void k_ch(const float* __restrict__ enc, unsigned short* __restrict__ dec){
    int i = blockIdx.x * 256 + threadIdx.x;       // MROWS*512
    int row = i >> 9, c = i & 511;
    const float* p = enc + (size_t)row * 8 * H2 + c;
    float s = 0.f;
#pragma unroll
    for (int t = 0; t < 8; t++) s += p[t * H2];
    dec[(size_t)row * DIN + 256 + c] = f2b(s * 0.125f);
}

// h0 into Hbuf[0], batch-major: Hbuf[0][b][c]. Clamp so bit14 (sentinel) can never be set.
__global__ void k_h0(const float* __restrict__ enc, unsigned short* __restrict__ Hbuf){
    int i = blockIdx.x * 256 + threadIdx.x;       // 64*512
    int b = i >> 9, c = i & 511;
    float v = (c < 256) ? enc[(size_t)b * SS * H2 + (size_t)(SS - 1) * H2 + c]
                        : enc[(size_t)b * SS * H2 + c];
    v = fminf(fmaxf(v, -1.875f), 1.875f);
    Hbuf[(size_t)b * 512 + c] = f2b(v);
}

// fill Hbuf steps 1..128 with sentinel (bit14 set => "not yet written").
// legit h = sigma*tanh in (-1,1): bf16 bit14 is clear for all |v| < 2.
__global__ void k_fill(uint4* __restrict__ p){
    int i = blockIdx.x * 256 + threadIdx.x;       // 2048*256 = 524288 uint4 = 8 MB
    uint4 v; v.x = v.y = v.z = v.w = 0x7FC07FC0u;
    p[i] = v;
}

// ---------------- fused conv GEMM + max-pool ----------------
// conv-over-taps == GEMM with K extended to taps*256 and A-row shifted by tap:
//   y[m][f] = sum_tap dot(X[m+tap], w_tap[f])  ->  A'[m][tap*256+d] = X[m+tap][d]
// The tap-sum accumulates inside the MFMA accumulator; pooling (max over p within
// each 8-row segment) + bias + ReLU run in the epilogue (lane max + shfl_xor(16)).
// Eliminates the 100MB G matrix write + re-read and 5 kernel launches.
// Block: 128 X-rows (16 segments), 128 filters, 3 convs sequentially.
__global__ __launch_bounds__(256) void gemm_conv_pool(
    const unsigned short* __restrict__ X, const unsigned short* __restrict__ Wf,
    const float* __restrict__ b1, const float* __restrict__ b2, const float* __restrict__ b3,
    unsigned short* __restrict__ dec)
{
    __shared__ unsigned short As[128][40];
    __shared__ unsigned short Bs[128][40];
    const int tid = threadIdx.x;
    const int m0 = blockIdx.x * 128;
    const int w = tid >> 6, lane = tid & 63;
    const int lm = lane & 15, quad = lane >> 4;
    const int wm = (w >> 1) * 64, wn = (w & 1) * 64;
    const int r0 = tid >> 2;            // 0..63
    const int kp = (tid & 3) * 8;       // 0,8,16,24

    const int woffs[3]  = {0, 128, 384};
    const int colofs[3] = {0, 128, 256};
    const float* biases[3] = {b1, b2, b3};

    for (int c = 0; c < 3; c++){
        const int taps = c + 1;
        const f32x4 z = {0.f, 0.f, 0.f, 0.f};
        f32x4 acc[4][4];
#pragma unroll
        for (int i = 0; i < 4; i++)
#pragma unroll
            for (int j = 0; j < 4; j++) acc[i][j] = z;

        for (int kc2 = 0; kc2 < taps * 256; kc2 += 32){
            int tap = kc2 >> 8, kc = kc2 & 255;
            int ra = m0 + r0 + tap;        if (ra > MX - 1) ra = MX - 1;   // clamp (result unused)
            int rb = m0 + 64 + r0 + tap;   if (rb > MX - 1) rb = MX - 1;
            int bw = woffs[c] + tap * 128;
            uint4 a0 = *(const uint4*)(X  + (size_t)ra * DD + kc + kp);
            uint4 a1 = *(const uint4*)(X  + (size_t)rb * DD + kc + kp);
            uint4 b0 = *(const uint4*)(Wf + (size_t)(bw + r0) * DD + kc + kp);
            uint4 b1v= *(const uint4*)(Wf + (size_t)(bw + 64 + r0) * DD + kc + kp);
            __syncthreads();
            *(uint4*)&As[r0][kp] = a0;
            *(uint4*)&As[64 + r0][kp] = a1;
            *(uint4*)&Bs[r0][kp] = b0;
            *(uint4*)&Bs[64 + r0][kp] = b1v;
            __syncthreads();
            bf16x8 af[4], bf[4];
#pragma unroll
            for (int mt = 0; mt < 4; mt++) af[mt] = *(const bf16x8*)&As[wm + mt * 16 + lm][quad * 8];
#pragma unroll
            for (int nt = 0; nt < 4; nt++) bf[nt] = *(const bf16x8*)&Bs[wn + nt * 16 + lm][quad * 8];
#pragma unroll
            for (int mt = 0; mt < 4; mt++)
#pragma unroll
                for (int nt = 0; nt < 4; nt++)
                    acc[mt][nt] = __builtin_amdgcn_mfma_f32_16x16x32_bf16(af[mt], bf[nt], acc[mt][nt], 0, 0, 0);
        }

        // --- pool epilogue: rows mrow = wm + mt*16 + quad*4 + r; seg = mrow>>3, p = mrow&7.
        // Thread covers p = (quad&1)*4 + r; partner lane (quad^1 -> lane^16) covers the other 4 p.
        const int pmax = 8 - taps;
        const float* bias = biases[c];
#pragma unroll
        for (int nt = 0; nt < 4; nt++){
            int f = wn + nt * 16 + lm;
            float bv = bias[f];
#pragma unroll
            for (int mt = 0; mt < 4; mt++){
                float mx = -1e30f;
#pragma unroll
                for (int r = 0; r < 4; r++){
                    int p = (quad & 1) * 4 + r;
                    if (p <= pmax) mx = fmaxf(mx, acc[mt][nt][r]);
                }
                float po = __shfl_xor(mx, 16);
                mx = fmaxf(mx, po);
                if (!(quad & 1)){
                    int seg = (m0 >> 3) + (wm >> 3) + mt * 2 + (quad >> 1);
                    float o = fmaxf(mx + bv, 0.f);
                    dec[(size_t)seg * DIN + 768 + colofs[c] + f] = f2b(o);
                }
            }
        }
    }
}

// ---- gates GEMM: epilogue writes the group/block-tiled layout ----
// Consumer block nb = grp*16+gb (grp = b>>4, gb = hcol>>5) owns local cols n = (hcol&31)*4 + gate.
// dst element: ((nb*128 + t)*128 + n)*16 + (b&15)   -> 4KB contiguous per (nb,t)
__global__ __launch_bounds__(256) void gemm_bt_gates(
    const unsigned short* __restrict__ A, const unsigned short* __restrict__ Bm,
    unsigned short* __restrict__ C, int M, int N, int K)
{
    __shared__ unsigned short As[128][40];
    __shared__ unsigned short Bs[128][40];
    const int tid = threadIdx.x;
    const int m0 = blockIdx.y * 128, n0 = blockIdx.x * 128;
    const int w = tid >> 6, lane = tid & 63;
    const int lm = lane & 15, quad = lane >> 4;
    const int wm = (w >> 1) * 64, wn = (w & 1) * 64;

    const f32x4 z = {0.f, 0.f, 0.f, 0.f};
    f32x4 acc[4][4];
#pragma unroll
    for (int i = 0; i < 4; i++)
#pragma unroll
        for (int j = 0; j < 4; j++) acc[i][j] = z;

    const int r0 = tid >> 2;
    const int kp = (tid & 3) * 8;

    for (int kc = 0; kc < K; kc += 32){
        uint4 a0 = *(const uint4*)(A + (size_t)(m0 + r0) * K + kc + kp);
        uint4 a1 = *(const uint4*)(A + (size_t)(m0 + 64 + r0) * K + kc + kp);
        uint4 b0 = *(const uint4*)(Bm + (size_t)(n0 + r0) * K + kc + kp);
        uint4 b1 = *(const uint4*)(Bm + (size_t)(n0 + 64 + r0) * K + kc + kp);
        __syncthreads();
        *(uint4*)&As[r0][kp] = a0;
        *(uint4*)&As[64 + r0][kp] = a1;
        *(uint4*)&Bs[r0][kp] = b0;
        *(uint4*)&Bs[64 + r0][kp] = b1;
        __syncthreads();
        bf16x8 af[4], bf[4];
#pragma unroll
        for (int mt = 0; mt < 4; mt++) af[mt] = *(const bf16x8*)&As[wm + mt * 16 + lm][quad * 8];
#pragma unroll
        for (int nt = 0; nt < 4; nt++) bf[nt] = *(const bf16x8*)&Bs[wn + nt * 16 + lm][quad * 8];
#pragma unroll
        for (int mt = 0; mt < 4; mt++)
#pragma unroll
            for (int nt = 0; nt < 4; nt++)
                acc[mt][nt] = __builtin_amdgcn_mfma_f32_16x16x32_bf16(af[mt], bf[nt], acc[mt][nt], 0, 0, 0);
    }
#pragma unroll
    for (int mt = 0; mt < 4; mt++){
        int mrow = m0 + wm + mt * 16 + quad * 4;
#pragma unroll
        for (int nt = 0; nt < 4; nt++){
            int ncol = n0 + wn + nt * 16 + lm;
            int g = ncol >> 9, c = ncol & 511;
            int gb = c >> 5, hcl = c & 31;
            int n = hcl * 4 + g;
#pragma unroll
            for (int r = 0; r < 4; r++){
                int m = mrow + r;                   // = b*128 + t
                int b = m >> 7, t = m & 127;
                int grp = b >> 4, bl = b & 15;
                size_t dst = (((size_t)(grp * 16 + gb) * NSEG + t) * 128 + n) * 16 + bl;
                C[dst] = f2b(acc[mt][nt][r]);
            }
        }
    }
}

// ---------------- persistent LSTM recurrence: 4 groups x 16 blocks, 8 waves/block ----------------
// Round-5 structure (best: 553us). New: amdgpu_waves_per_eu(2,2) pins occupancy at exactly
// 2 waves/EU -> register budget 256/wave, removing the allocator's occupancy motive for
// evicting the 64-VGPR W panel (rounds 3/5/6 failed at VGPR_Count 64-124: heuristic budget,
// not rematerialization, was the blocker). In-loop "+v" pin keeps W opaque. MFMA chain split
// into two 8-deep chains to halve dependent-latency on the serial path.
// Sync: sentinel-on-data (bit14), fan-in 16, s_sleep backoff. One barrier/step.
// Hbuf layout per step: [b:64][c:512] bf16, batch-major.
// gxt layout: [nb:64][t:128][n:128][bl:16], 4KB chunk per (nb,t).
__global__ __attribute__((amdgpu_flat_work_group_size(512, 512), amdgpu_waves_per_eu(2, 2)))
void k_lstm(
    const unsigned short* __restrict__ gxt,  // blocked gate pre-activations, bf16
    const unsigned short* __restrict__ Whh,  // [2048][512] bf16
    unsigned short* __restrict__ Hbuf)       // [129][64*512]
{
    __shared__ unsigned short h_lds[2][16 * 512];   // 2 x 16KB, double-buffered

    const int tid = threadIdx.x;
    const int nb = blockIdx.x;
    const int grp = nb >> 4, gb = nb & 15;
    const int w = tid >> 6, lane = tid & 63, lm = lane & 15, quad = lane >> 4;
    const int g = lm & 3;

    // --- W fragments in registers: wave w owns local gate-cols n = w*16 + lm.
    // global W row = (n&3)*512 + gb*32 + (n>>2); fragment ks: cols ks*32 + quad*8 .. +8
    bf16x8 wf[16];
    {
        int n = w * 16 + lm;
        const unsigned short* p = Whh + (size_t)((n & 3) * 512 + gb * 32 + (n >> 2)) * H2 + quad * 8;
#pragma unroll
        for (int ks = 0; ks < 16; ks++) wf[ks] = *(const bf16x8*)(p + ks * 32);
    }

    float cst[4] = {0.f, 0.f, 0.f, 0.f};

    union Chunk { unsigned long long q[2]; uint4 u4; };

    for (int t = 0; t < NSEG; t++){
        // --- pin W resident (budget is 256 now; spilling is strictly worse) ---
#pragma unroll
        for (int ks = 0; ks < 16; ks++) asm volatile("" : "+v"(wf[ks]));

        // --- issue this thread's 2 h-chunks (16B each) of the group's 16KB region ---
        const unsigned short* hsrc = Hbuf + (size_t)t * (BB * H2) + (size_t)grp * (16 * H2);
        Chunk ch[2];
#pragma unroll
        for (int j = 0; j < 2; j++){
            const unsigned long long* p = (const unsigned long long*)(hsrc + (size_t)(j * 512 + tid) * 8);
            ch[j].q[0] = __hip_atomic_load(p,     __ATOMIC_RELAXED, __HIP_MEMORY_SCOPE_AGENT);
            ch[j].q[1] = __hip_atomic_load(p + 1, __ATOMIC_RELAXED, __HIP_MEMORY_SCOPE_AGENT);
        }

        // --- gate pre-activations (normal cached loads, independent) ---
        const unsigned short* gchunk = gxt + ((size_t)nb * NSEG + t) * 2048;
        ushort4 pr = *(const ushort4*)(gchunk + (w * 16 + lm) * 16 + quad * 4);

        // --- sentinel poll with backoff: retry only missing chunks ---
        unsigned pend = 0x3u;
        while (pend){
            unsigned np = 0;
#pragma unroll
            for (int j = 0; j < 2; j++){
                if (pend & (1u << j)){
                    if (((ch[j].q[0] | ch[j].q[1]) & 0x4000400040004000ULL) != 0ULL){
                        const unsigned long long* p = (const unsigned long long*)(hsrc + (size_t)(j * 512 + tid) * 8);
                        ch[j].q[0] = __hip_atomic_load(p,     __ATOMIC_RELAXED, __HIP_MEMORY_SCOPE_AGENT);
                        ch[j].q[1] = __hip_atomic_load(p + 1, __ATOMIC_RELAXED, __HIP_MEMORY_SCOPE_AGENT);
                        np |= 1u << j;
                    }
                }
            }
            pend = np;
            if (pend) __builtin_amdgcn_s_sleep(1);
        }

        // --- stage h to LDS, XOR-swizzled (row = byte>>10; byte ^= (row&7)<<4) ---
        char* hb = (char*)&h_lds[t & 1][0];
#pragma unroll
        for (int j = 0; j < 2; j++){
            unsigned addr = (unsigned)(j * 512 + tid) * 16u;
            addr ^= ((addr >> 10) & 7u) << 4;
            *(uint4*)(hb + addr) = ch[j].u4;
        }
        __syncthreads();

        // --- MFMA: A (h) from LDS, B (W) from registers; two 8-deep chains ---
        const unsigned hrowb = (unsigned)lm << 10;
        const unsigned swz = (unsigned)(lm & 7) << 4;
        f32x4 acc0 = {0.f, 0.f, 0.f, 0.f}, acc1 = {0.f, 0.f, 0.f, 0.f};
#pragma unroll
        for (int ks = 0; ks < 16; ks += 2){
            unsigned colb0 = ((unsigned)ks << 6) + ((unsigned)quad << 4);
            unsigned colb1 = colb0 + 64u;
            bf16x8 av0 = *(const bf16x8*)(hb + ((hrowb + colb0) ^ swz));
            bf16x8 av1 = *(const bf16x8*)(hb + ((hrowb + colb1) ^ swz));
            acc0 = __builtin_amdgcn_mfma_f32_16x16x32_bf16(av0, wf[ks],     acc0, 0, 0, 0);
            acc1 = __builtin_amdgcn_mfma_f32_16x16x32_bf16(av1, wf[ks + 1], acc1, 0, 0, 0);
        }

        // --- epilogue: gather i/f/g/o across the 4-lane gate group (g = lm&3) ---
        const unsigned short* prs = (const unsigned short*)&pr;
        unsigned short hv4[4];
#pragma unroll
        for (int r = 0; r < 4; r++){
            float a = acc0[r] + acc1[r] + b2f(prs[r]);
            float bsw = __shfl_xor(a, 1);
            float p  = (g & 1) ? bsw : a;     // i or g
            float qq = (g & 1) ? a : bsw;     // f or o
            float c2 = __shfl_xor(p, 2);
            float d2 = __shfl_xor(qq, 2);
            float iv = (g & 2) ? c2 : p;
            float gv = (g & 2) ? p  : c2;
            float fv = (g & 2) ? d2 : qq;
            float ov = (g & 2) ? qq : d2;
            float si = fsig(iv), sf = fsig(fv), so = fsig(ov);
            float cn = sf * cst[r] + si * ftanh(gv);
            cst[r] = cn;
            unsigned short hv = f2b(so * ftanh(cn));
            if (hv & 0x4000u) hv = 0;         // insurance: never emit a sentinel pattern
            hv4[r] = hv;
        }

        // --- publish: shfl-pack 4 cols -> 8B stores (lane lm==0 per quad stores) ---
#pragma unroll
        for (int r = 0; r < 4; r++){
            unsigned v01 = (unsigned)hv4[r] | ((unsigned)(unsigned short)__shfl_xor((int)hv4[r], 4) << 16);
            unsigned v23 = (unsigned)__shfl_xor((int)v01, 8);
            unsigned long long outq = (unsigned long long)v01 | ((unsigned long long)v23 << 32);
            if (lm == 0){
                int bt = grp * 16 + quad * 4 + r;
                unsigned long long* dp = (unsigned long long*)
                    (Hbuf + (size_t)(t + 1) * (BB * H2) + (size_t)bt * H2 + gb * 32 + w * 4);
                __hip_atomic_store(dp, outq, __ATOMIC_RELAXED, __HIP_MEMORY_SCOPE_AGENT);
            }
        }
        asm volatile("" ::: "memory");   // pin the h stores inside this iteration
    }
}

// ---------------- output projection + log_softmax ----------------
__global__ __launch_bounds__(256) void k_out(
    const unsigned short* __restrict__ Hbuf, const float* __restrict__ Wt, float* __restrict__ out)
{
    __shared__ float hsh[4][H2];
    const int w = threadIdx.x >> 6, lane = threadIdx.x & 63;
    const int row = blockIdx.x * 4 + w;          // 0..8191 = b*128 + t
    const int b = row >> 7, t = row & 127;
    const unsigned short* hp = Hbuf + (size_t)(t + 1) * (BB * H2) + (size_t)b * H2;
    uint4 hv = *(const uint4*)(hp + lane * 8);
    const unsigned short* hs = (const unsigned short*)&hv;
#pragma unroll
    for (int i = 0; i < 8; i++) hsh[w][lane * 8 + i] = b2f(hs[i]);
    __syncthreads();
    float acc = 0.f;
#pragma unroll 8
    for (int k = 0; k < H2; k++)
        acc = fmaf(hsh[w][k], Wt[k * 64 + lane], acc);
    float m = acc;
#pragma unroll
    for (int off = 32; off; off >>= 1) m = fmaxf(m, __shfl_xor(m, off));
    float e = expf(acc - m), s = e;
#pragma unroll
    for (int off = 32; off; off >>= 1) s += __shfl_xor(s, off);
    out[(size_t)row * TT + lane] = acc - m - logf(s);
}

// ---------------- launcher ----------------
extern "C" void kernel_launch(void* const* d_in, const int* in_sizes, int n_in,
                              void* d_out, int out_size, void* d_ws, size_t ws_size,
                              hipStream_t stream)
{
    const int*   wid = (const int*)d_in[0];
    const float* emb = (const float*)d_in[1];
    const float* enc = (const float*)d_in[2];
    const float* wc1 = (const float*)d_in[3];
    const float* bc1 = (const float*)d_in[4];
    const float* wc2 = (const float*)d_in[5];
    const float* bc2 = (const float*)d_in[6];
    const float* wc3 = (const float*)d_in[7];
    const float* bc3 = (const float*)d_in[8];
    const float* wih = (const float*)d_in[9];
    const float* whh = (const float*)d_in[10];
    const float* wfc = (const float*)d_in[11];

    char* ws = (char*)d_ws;
    size_t off = 0;
    auto alloc = [&](size_t bytes) -> void* {
        void* p = ws + off; off += (bytes + 255) & ~(size_t)255; return p;
    };
    unsigned short* X    = (unsigned short*)alloc((size_t)MX * DD * 2);      // 33.5 MB (reused as Hbuf)
    unsigned short* dec  = (unsigned short*)alloc((size_t)MROWS * DIN * 2);  // 18.9 MB
    unsigned short* Gb   = (unsigned short*)alloc((size_t)MX * 384 * 2);     // 50.3 MB (gates region)
    unsigned short* Wfb  = (unsigned short*)alloc((size_t)768 * 256 * 2);
    unsigned short* Wihb = (unsigned short*)alloc((size_t)G4 * DIN * 2);
    unsigned short* Whhb = (unsigned short*)alloc((size_t)G4 * H2 * 2);
    float*          Wfct = (float*)alloc((size_t)H2 * TT * 4);
    unsigned short* Hbuf  = X;    // X dead after gemm_conv_pool
    unsigned short* gates = Gb;

    k_cvt<<<(G4 * DIN + 255) / 256, 256, 0, stream>>>(wih, Wihb, G4 * DIN);
    k_cvt<<<(G4 * H2 + 255) / 256, 256, 0, stream>>>(whh, Whhb, G4 * H2);
    k_wf<<<768, 256, 0, stream>>>(wc1, wc2, wc3, Wfb);
    k_tr_wfc<<<128, 256, 0, stream>>>(wfc, Wfct);
    k_gather<<<MX / 4, 256, 0, stream>>>(wid, emb, X);
    k_cw<<<MROWS, 256, 0, stream>>>(X, dec);
    k_ch<<<MROWS * 2, 256, 0, stream>>>(enc, dec);

    // fused conv GEMM + pool: replaces 3x gemm_bt + 3x k_pool (no G materialization)
    gemm_conv_pool<<<512, 256, 0, stream>>>(X, Wfb, bc1, bc2, bc3, dec);

    // X dead after gemm_conv_pool: init Hbuf[0] (h0) and sentinel-fill steps 1..128
    k_h0<<<BB * H2 / 256, 256, 0, stream>>>(enc, Hbuf);
    k_fill<<<2048, 256, 0, stream>>>((uint4*)(Hbuf + BB * H2));

    gemm_bt_gates<<<dim3(16, 64), 256, 0, stream>>>(dec, Wihb, gates, MROWS, G4, DIN);
    k_lstm<<<64, 512, 0, stream>>>(gates, Whhb, Hbuf);
    k_out<<<2048, 256, 0, stream>>>(Hbuf, Wfct, (float*)d_out);
}